// Round 5
// baseline (153373.865 us; speedup 1.0000x reference)
//
#include <hip/hip_runtime.h>

// ---- problem constants ----
constexpr int SQ = 8192;   // sequence length
constexpr int HD = 256;    // hidden size H
constexpr int NG = 1024;   // 4H (gate width)

typedef __fp16 h2 __attribute__((ext_vector_type(2)));
typedef unsigned int uint;

__device__ __forceinline__ float sigm_f(float x) {
  float e = __builtin_amdgcn_exp2f(-1.4426950408889634f * x);
  return __builtin_amdgcn_rcpf(1.0f + e);
}
__device__ __forceinline__ float tanh_f(float x) {
  float e = __builtin_amdgcn_exp2f(2.885390081777927f * x);
  return 1.0f - 2.0f * __builtin_amdgcn_rcpf(1.0f + e);
}
__device__ __forceinline__ h2 bch2(uint v) { return __builtin_bit_cast(h2, v); }
__device__ __forceinline__ uint pk(float a, float b) {
  return __builtin_bit_cast(uint, __builtin_amdgcn_cvt_pkrtz(a, b));
}

// =====================================================================
// xp GEMM: out[d][m][n] = sum_k A[m][k] * W[d][k][n] + bias[d][n]
// =====================================================================
__global__ __launch_bounds__(256) void gemm_xp(const float* __restrict__ A, int K,
                                               const float* __restrict__ W,
                                               const float* __restrict__ bias,
                                               float* __restrict__ out) {
  __shared__ float Al[16][64];  // [k][m]
  __shared__ float Bl[16][64];  // [k][n]
  const int tid = threadIdx.x;
  const int bm = blockIdx.x * 64;
  const int d  = blockIdx.y >> 4;
  const int bn = (blockIdx.y & 15) * 64;
  const float* Wd = W + (size_t)d * K * NG;
  const float* bd = bias + (size_t)d * NG;
  float* outd = out + (size_t)d * SQ * NG;

  const int m4 = (tid >> 4) << 2;
  const int n4 = (tid & 15) << 2;
  const int am = tid >> 2, ak = (tid & 3) << 2;
  const int bk = tid >> 4, bnn = (tid & 15) << 2;

  float acc[4][4] = {};
  for (int kt = 0; kt < K; kt += 16) {
    float4 av = *(const float4*)(A + (size_t)(bm + am) * K + kt + ak);
    float4 bv = *(const float4*)(Wd + (size_t)(kt + bk) * NG + bn + bnn);
    __syncthreads();
    Al[ak + 0][am] = av.x;
    Al[ak + 1][am] = av.y;
    Al[ak + 2][am] = av.z;
    Al[ak + 3][am] = av.w;
    *(float4*)&Bl[bk][bnn] = bv;
    __syncthreads();
#pragma unroll
    for (int k = 0; k < 16; ++k) {
      float4 a = *(const float4*)&Al[k][m4];
      float4 b = *(const float4*)&Bl[k][n4];
      float ar[4] = {a.x, a.y, a.z, a.w};
      float br[4] = {b.x, b.y, b.z, b.w};
#pragma unroll
      for (int i = 0; i < 4; ++i)
#pragma unroll
        for (int jj = 0; jj < 4; ++jj)
          acc[i][jj] = fmaf(ar[i], br[jj], acc[i][jj]);
    }
  }
#pragma unroll
  for (int i = 0; i < 4; ++i) {
    float4 o;
    o.x = acc[i][0] + bd[bn + n4 + 0];
    o.y = acc[i][1] + bd[bn + n4 + 1];
    o.z = acc[i][2] + bd[bn + n4 + 2];
    o.w = acc[i][3] + bd[bn + n4 + 3];
    *(float4*)(outd + (size_t)(bm + m4 + i) * NG + bn + n4) = o;
  }
}

// =====================================================================
// LSTM recurrence v5: 1 workgroup/direction, 1024 threads (16 waves).
// Thread (u, s):  u = w*16 + (l&15)  (unit 0..255),  s = l>>4 (K-quarter).
// Owns ALL 4 gate columns {u, 256+u, 512+u, 768+u} over rows [64s, 64s+64):
//   -> 4 x 32 h2 = 128 weight VGPRs, ALL architectural (no LDS weights).
// Per step: 8 broadcast b128 h-reads (bank-padded layout), 128 fdot2,
// 2-level shfl_xor K-combine; lanes l<16 hold all 4 gates of unit u ->
// LOCAL c/h update (no gate exchange), pack h f16x2, write to the
// parity-flipped h buffer. ONE barrier per step.
// h LDS layout: hldsd[parity][144] dwords; K-quarter region s at dword
// 36*s (+4 pad dwords -> the 4 broadcast addresses hit distinct banks).
// =====================================================================
__global__ __launch_bounds__(1024, 1) void lstm_rec5(const float* __restrict__ Whh,
                                                     const float* __restrict__ xp,
                                                     float* __restrict__ obuf) {
  __shared__ uint hldsd[2][144];   // 1.15KB total
  const int d = blockIdx.x;
  const int j = threadIdx.x;
  const int w = j >> 6;
  const int l = j & 63;
  const int u = w * 16 + (l & 15);      // unit
  const int s = l >> 4;                 // K-quarter
  const float* W   = Whh + (size_t)d * HD * NG;
  const float* xpd = xp + (size_t)d * SQ * NG;

  // ---- one-time weight load: rows [64s,64s+64) x cols {u+256i} ----
  h2 wr[4][32];
#pragma unroll
  for (int i = 0; i < 4; ++i) {
    const float* Wc = W + (size_t)(64 * s) * NG + u + 256 * i;
#pragma unroll
    for (int k = 0; k < 32; ++k)
      wr[i][k] = __builtin_amdgcn_cvt_pkrtz(Wc[(size_t)(2 * k) * NG],
                                            Wc[(size_t)(2 * k + 1) * NG]);
  }

  if (j < 288) ((uint*)hldsd)[j] = 0u;
  __syncthreads();

  const int fwd = (d == 0) ? 1 : 0;
  int t = fwd ? 0 : SQ - 1;
  const int dt = fwd ? 1 : -1;
  float cc = 0.0f;
  int p = 0;

  float xc[4] = {}, xn[4] = {};
  if (l < 16) {
#pragma unroll
    for (int i = 0; i < 4; ++i) xc[i] = xpd[(size_t)t * NG + u + 256 * i];
  }

  for (int step = 0; step < SQ; ++step) {
    if (l < 16 && step + 1 < SQ) {
#pragma unroll
      for (int i = 0; i < 4; ++i) xn[i] = xpd[(size_t)(t + dt) * NG + u + 256 * i];
    }

    // ---- dots: rows [64s, 64s+64) ----
    const uint4* hb = (const uint4*)&hldsd[p][36 * s];
    float acc[4] = {0.0f, 0.0f, 0.0f, 0.0f};
#pragma unroll
    for (int q = 0; q < 8; ++q) {
      uint4 hq = hb[q];
      h2 hx = bch2(hq.x), hy = bch2(hq.y), hz = bch2(hq.z), hw = bch2(hq.w);
#pragma unroll
      for (int i = 0; i < 4; ++i) {
        acc[i] = __builtin_amdgcn_fdot2(wr[i][4 * q + 0], hx, acc[i], false);
        acc[i] = __builtin_amdgcn_fdot2(wr[i][4 * q + 1], hy, acc[i], false);
        acc[i] = __builtin_amdgcn_fdot2(wr[i][4 * q + 2], hz, acc[i], false);
        acc[i] = __builtin_amdgcn_fdot2(wr[i][4 * q + 3], hw, acc[i], false);
      }
    }

    // ---- K-combine over s (lane bits 4,5) ----
#pragma unroll
    for (int i = 0; i < 4; ++i) {
      acc[i] += __shfl_xor(acc[i], 16);
      acc[i] += __shfl_xor(acc[i], 32);
    }

    // ---- local update on lanes 0..15 (all 4 gates of unit u) ----
    if (l < 16) {
      float iv = sigm_f(acc[0] + xc[0]);
      float fv = sigm_f(acc[1] + xc[1]);
      float gv = tanh_f(acc[2] + xc[2]);
      float ov = sigm_f(acc[3] + xc[3]);
      cc = fv * cc + iv * gv;
      float hv = ov * tanh_f(cc);
      obuf[(size_t)t * 512 + (d << 8) + u] = hv;
      float hn = __shfl_down(hv, 1);
      if (!(l & 1)) {
        const int word = u >> 1;                       // 0..127
        hldsd[p ^ 1][36 * (word >> 5) + (word & 31)] = pk(hv, hn);
      }
    }
    __syncthreads();   // h(p^1) visible; everyone done reading h(p)

    p ^= 1;
#pragma unroll
    for (int i = 0; i < 4; ++i) xc[i] = xn[i];
    t += dt;
  }
}

// =====================================================================
// classifier head
// =====================================================================
__global__ void cls_k(const float* __restrict__ buf, const float* __restrict__ w1,
                      const float* __restrict__ b1, const float* __restrict__ w2,
                      const float* __restrict__ b2, float* __restrict__ out) {
  __shared__ float feat[512];
  __shared__ float hid[32];
  const int t = threadIdx.x;
  feat[t] = (t < 256) ? buf[(size_t)(SQ - 1) * 512 + t] : buf[t];
  __syncthreads();
  if (t < 32) {
    float a = b1[t];
    for (int k = 0; k < 512; ++k) a = fmaf(feat[k], w1[k * 32 + t], a);
    hid[t] = a;
  }
  __syncthreads();
  if (t < 2) {
    float a = b2[t];
    for (int k = 0; k < 32; ++k) a = fmaf(hid[k], w2[k * 2 + t], a);
    out[t] = a;
  }
}

// =====================================================================
extern "C" void kernel_launch(void* const* d_in, const int* in_sizes, int n_in,
                              void* d_out, int out_size, void* d_ws, size_t ws_size,
                              hipStream_t stream) {
  const float* x     = (const float*)d_in[0];
  const float* w_ih0 = (const float*)d_in[1];
  const float* w_hh0 = (const float*)d_in[2];
  const float* b0    = (const float*)d_in[3];
  const float* w_ih  = (const float*)d_in[4];
  const float* w_hh  = (const float*)d_in[5];
  const float* b     = (const float*)d_in[6];
  const float* w1    = (const float*)d_in[7];
  const float* b1    = (const float*)d_in[8];
  const float* w2    = (const float*)d_in[9];
  const float* b2    = (const float*)d_in[10];

  float* xp   = (float*)d_ws;                       // [2][SQ][NG] = 64MB
  float* bufA = xp + (size_t)2 * SQ * NG;           // [SQ][512]   = 16MB
  float* bufB = bufA + (size_t)SQ * 512;            // [SQ][512]   = 16MB

  const dim3 ggrid(SQ / 64, 32);

  // layer 0
  gemm_xp<<<ggrid, 256, 0, stream>>>(x, 1024, w_ih0, b0, xp);
  lstm_rec5<<<2, 1024, 0, stream>>>(w_hh0, xp, bufA);

  // layers 1..4
  float* cur = bufA;
  float* nxt = bufB;
  for (int lyr = 0; lyr < 4; ++lyr) {
    gemm_xp<<<ggrid, 256, 0, stream>>>(cur, 512, w_ih + (size_t)lyr * 2 * 512 * 1024,
                                       b + (size_t)lyr * 2 * 1024, xp);
    lstm_rec5<<<2, 1024, 0, stream>>>(w_hh + (size_t)lyr * 2 * 256 * 1024, xp, nxt);
    float* tmp = cur; cur = nxt; nxt = tmp;
  }

  cls_k<<<1, 512, 0, stream>>>(cur, w1, b1, w2, b2, (float*)d_out);
}

// Round 6
// 118971.106 us; speedup vs baseline: 1.2892x; 1.2892x over previous
//
#include <hip/hip_runtime.h>

// ---- problem constants ----
constexpr int SQ = 8192;   // sequence length
constexpr int HD = 256;    // hidden size H
constexpr int NG = 1024;   // 4H (gate width)

typedef __fp16 h2 __attribute__((ext_vector_type(2)));
typedef unsigned int uint;

__device__ __forceinline__ float sigm_f(float x) {
  float e = __builtin_amdgcn_exp2f(-1.4426950408889634f * x);
  return __builtin_amdgcn_rcpf(1.0f + e);
}
__device__ __forceinline__ float tanh_f(float x) {
  float e = __builtin_amdgcn_exp2f(2.885390081777927f * x);
  return 1.0f - 2.0f * __builtin_amdgcn_rcpf(1.0f + e);
}
__device__ __forceinline__ h2 bch2(uint v) { return __builtin_bit_cast(h2, v); }
__device__ __forceinline__ uint pk(float a, float b) {
  return __builtin_bit_cast(uint, __builtin_amdgcn_cvt_pkrtz(a, b));
}

// =====================================================================
// xp GEMM: out[d][m][n] = sum_k A[m][k] * W[d][k][n] + bias[d][n]
// =====================================================================
__global__ __launch_bounds__(256) void gemm_xp(const float* __restrict__ A, int K,
                                               const float* __restrict__ W,
                                               const float* __restrict__ bias,
                                               float* __restrict__ out) {
  __shared__ float Al[16][64];  // [k][m]
  __shared__ float Bl[16][64];  // [k][n]
  const int tid = threadIdx.x;
  const int bm = blockIdx.x * 64;
  const int d  = blockIdx.y >> 4;
  const int bn = (blockIdx.y & 15) * 64;
  const float* Wd = W + (size_t)d * K * NG;
  const float* bd = bias + (size_t)d * NG;
  float* outd = out + (size_t)d * SQ * NG;

  const int m4 = (tid >> 4) << 2;
  const int n4 = (tid & 15) << 2;
  const int am = tid >> 2, ak = (tid & 3) << 2;
  const int bk = tid >> 4, bnn = (tid & 15) << 2;

  float acc[4][4] = {};
  for (int kt = 0; kt < K; kt += 16) {
    float4 av = *(const float4*)(A + (size_t)(bm + am) * K + kt + ak);
    float4 bv = *(const float4*)(Wd + (size_t)(kt + bk) * NG + bn + bnn);
    __syncthreads();
    Al[ak + 0][am] = av.x;
    Al[ak + 1][am] = av.y;
    Al[ak + 2][am] = av.z;
    Al[ak + 3][am] = av.w;
    *(float4*)&Bl[bk][bnn] = bv;
    __syncthreads();
#pragma unroll
    for (int k = 0; k < 16; ++k) {
      float4 a = *(const float4*)&Al[k][m4];
      float4 b = *(const float4*)&Bl[k][n4];
      float ar[4] = {a.x, a.y, a.z, a.w};
      float br[4] = {b.x, b.y, b.z, b.w};
#pragma unroll
      for (int i = 0; i < 4; ++i)
#pragma unroll
        for (int jj = 0; jj < 4; ++jj)
          acc[i][jj] = fmaf(ar[i], br[jj], acc[i][jj]);
    }
  }
#pragma unroll
  for (int i = 0; i < 4; ++i) {
    float4 o;
    o.x = acc[i][0] + bd[bn + n4 + 0];
    o.y = acc[i][1] + bd[bn + n4 + 1];
    o.z = acc[i][2] + bd[bn + n4 + 2];
    o.w = acc[i][3] + bd[bn + n4 + 3];
    *(float4*)(outd + (size_t)(bm + m4 + i) * NG + bn + n4) = o;
  }
}

// =====================================================================
// LSTM recurrence v6: 1 workgroup/direction, 1024 threads (16 waves).
// Thread j owns gate column j COMPLETELY: 128 h2 weight regs (rows
// 0..255 paired). __launch_bounds__(1024,2) -> 256-reg cap, pressure
// ~160 fits in ARCHITECTURAL VGPRs (no AGPR split, no copies).
// No cross-lane combine at all. h read as 32 wave-uniform ds_read_b128
// broadcasts. xp[t][j] coalesced, prefetched 1 step ahead.
// Gate exchange via glds[1024]; threads<256 do the c/h update.
// 2 barriers/step.
// =====================================================================
__global__ __launch_bounds__(1024, 2) void lstm_rec6(const float* __restrict__ Whh,
                                                     const float* __restrict__ xp,
                                                     float* __restrict__ obuf) {
  __shared__ float glds[1024];   // gate value per column
  __shared__ uint  hl[128];      // h packed f16x2: dword r = (h[2r], h[2r+1])
  const int d = blockIdx.x;
  const int j = threadIdx.x;
  const float* W   = Whh + (size_t)d * HD * NG;
  const float* xpd = xp + (size_t)d * SQ * NG;

  // ---- one-time weight load: full column j, rows paired ----
  h2 wr[128];
#pragma unroll
  for (int k = 0; k < 128; ++k)
    wr[k] = __builtin_amdgcn_cvt_pkrtz(W[(size_t)(2 * k) * NG + j],
                                       W[(size_t)(2 * k + 1) * NG + j]);

  if (j < 128) hl[j] = 0u;
  __syncthreads();

  const int fwd = (d == 0) ? 1 : 0;
  int t = fwd ? 0 : SQ - 1;
  const int dt = fwd ? 1 : -1;
  const int qg = j >> 8;            // gate index of this column (wave-uniform)
  const bool is_tanh = (qg == 2);
  float cc = 0.0f;
  float xc = xpd[(size_t)t * NG + j];

  for (int step = 0; step < SQ; ++step) {
    float xn = (step + 1 < SQ) ? xpd[(size_t)(t + dt) * NG + j] : 0.0f;

    // ---- dots: 32 uniform-address b128 broadcasts, 128 fdot2 ----
    const uint4* hb = (const uint4*)hl;
    float a0 = 0.0f, a1 = 0.0f, a2 = 0.0f, a3 = 0.0f;
#pragma unroll
    for (int q = 0; q < 32; ++q) {
      uint4 hq = hb[q];
      a0 = __builtin_amdgcn_fdot2(wr[4 * q + 0], bch2(hq.x), a0, false);
      a1 = __builtin_amdgcn_fdot2(wr[4 * q + 1], bch2(hq.y), a1, false);
      a2 = __builtin_amdgcn_fdot2(wr[4 * q + 2], bch2(hq.z), a2, false);
      a3 = __builtin_amdgcn_fdot2(wr[4 * q + 3], bch2(hq.w), a3, false);
    }
    float pre = ((a0 + a1) + (a2 + a3)) + xc;
    float act = is_tanh ? tanh_f(pre) : sigm_f(pre);
    glds[j] = act;
    __syncthreads();   // B1: gates visible; all dots done reading hl

    if (j < 256) {     // waves 0-3 (one per SIMD): state update for unit j
      float iv = glds[j];
      float fv = glds[256 + j];
      float gv = glds[512 + j];
      float ov = glds[768 + j];
      cc = fv * cc + iv * gv;
      float hv = ov * tanh_f(cc);
      obuf[(size_t)t * 512 + (d << 8) + j] = hv;
      float hn = __shfl_down(hv, 1);
      if (!(j & 1)) hl[j >> 1] = pk(hv, hn);
    }
    __syncthreads();   // B2: new h visible for next step

    xc = xn;
    t += dt;
  }
}

// =====================================================================
// classifier head
// =====================================================================
__global__ void cls_k(const float* __restrict__ buf, const float* __restrict__ w1,
                      const float* __restrict__ b1, const float* __restrict__ w2,
                      const float* __restrict__ b2, float* __restrict__ out) {
  __shared__ float feat[512];
  __shared__ float hid[32];
  const int t = threadIdx.x;
  feat[t] = (t < 256) ? buf[(size_t)(SQ - 1) * 512 + t] : buf[t];
  __syncthreads();
  if (t < 32) {
    float a = b1[t];
    for (int k = 0; k < 512; ++k) a = fmaf(feat[k], w1[k * 32 + t], a);
    hid[t] = a;
  }
  __syncthreads();
  if (t < 2) {
    float a = b2[t];
    for (int k = 0; k < 32; ++k) a = fmaf(hid[k], w2[k * 2 + t], a);
    out[t] = a;
  }
}

// =====================================================================
extern "C" void kernel_launch(void* const* d_in, const int* in_sizes, int n_in,
                              void* d_out, int out_size, void* d_ws, size_t ws_size,
                              hipStream_t stream) {
  const float* x     = (const float*)d_in[0];
  const float* w_ih0 = (const float*)d_in[1];
  const float* w_hh0 = (const float*)d_in[2];
  const float* b0    = (const float*)d_in[3];
  const float* w_ih  = (const float*)d_in[4];
  const float* w_hh  = (const float*)d_in[5];
  const float* b     = (const float*)d_in[6];
  const float* w1    = (const float*)d_in[7];
  const float* b1    = (const float*)d_in[8];
  const float* w2    = (const float*)d_in[9];
  const float* b2    = (const float*)d_in[10];

  float* xp   = (float*)d_ws;                       // [2][SQ][NG] = 64MB
  float* bufA = xp + (size_t)2 * SQ * NG;           // [SQ][512]   = 16MB
  float* bufB = bufA + (size_t)SQ * 512;            // [SQ][512]   = 16MB

  const dim3 ggrid(SQ / 64, 32);

  // layer 0
  gemm_xp<<<ggrid, 256, 0, stream>>>(x, 1024, w_ih0, b0, xp);
  lstm_rec6<<<2, 1024, 0, stream>>>(w_hh0, xp, bufA);

  // layers 1..4
  float* cur = bufA;
  float* nxt = bufB;
  for (int lyr = 0; lyr < 4; ++lyr) {
    gemm_xp<<<ggrid, 256, 0, stream>>>(cur, 512, w_ih + (size_t)lyr * 2 * 512 * 1024,
                                       b + (size_t)lyr * 2 * 1024, xp);
    lstm_rec6<<<2, 1024, 0, stream>>>(w_hh + (size_t)lyr * 2 * 256 * 1024, xp, nxt);
    float* tmp = cur; cur = nxt; nxt = tmp;
  }

  cls_k<<<1, 512, 0, stream>>>(cur, w1, b1, w2, b2, (float*)d_out);
}